// Round 13
// baseline (542.252 us; speedup 1.0000x reference)
//
#include <hip/hip_runtime.h>
#include <hip/hip_fp16.h>
#include <hip/hip_cooperative_groups.h>

namespace cg = cooperative_groups;

// Regrid: ONE cooperative preproc dispatch + r9's proven hot path.
// y[n, b] = sum_{k: rows[k]==b} w[k] * x[n, flip(cols[k])]
// x: (140, 721*1440) f32, rows/cols: (260640,) i32, w: f32, out: (140, 181*360) f32.
//
// 3 dispatches:
//  1) preproc (cooperative): zero counts -> dual histogram (64B-line bucket +
//     row) -> parallel 3-step scans -> permute perm[j_cf] = (cf, w, j_row).
//  2) gather (r9 verbatim, PLAIN loads): thread = one cf-sorted nnz; 140
//     scalar x loads (sorted lanes -> coalescer merges lines, L1 absorbs 4x
//     line reuse, blocks sweep planes in lockstep -> FETCH ~584MB, proven r8;
//     ~3.3 TB/s = random-access ceiling per r5's 3.6 TB/s datum), packs 70
//     fp16 pairs, writes one full 384B g row at the row-sorted slot.
//  3) reduce (r9 verbatim): g rows for b contiguous -> fully sequential
//     reads, f32 accumulate, LDS transpose, coalesced out stores.
// No global atomics in hot phases; d_out fully overwritten -> no zeroing.

#define NXS 1440
#define NYS 721
#define N_A_CONST (721 * 1440)
#define N_B_CONST (181 * 360)
#define NBUCK (N_A_CONST / 16)          // 64,890 64B-line buckets
#define NCHA ((NBUCK + 255) / 256)      // 254 scan chunks for boff
#define NCHB ((N_B_CONST + 255) / 256)  // 255 scan chunks for roff
#define NFIELD 140
#define NPAIR (NFIELD / 2)              // 70 packed fp16 pairs
#define GDW 96                          // g row stride in dwords (384B = 6 lines)
#define PRE_BLOCKS 512

__device__ __forceinline__ int flip_col(int c) {
    int iy = c / NXS;
    int ix = c - iy * NXS;
    return (NYS - 1 - iy) * NXS + ix;
}

__device__ __forceinline__ int block_scan_256(int v, int* wsum) {
    int lane = threadIdx.x & 63;
    int wv = threadIdx.x >> 6;
    int incl = v;
    #pragma unroll
    for (int off = 1; off < 64; off <<= 1) {
        int u = __shfl_up(incl, off, 64);
        if (lane >= off) incl += u;
    }
    if (lane == 63) wsum[wv] = incl;
    __syncthreads();
    int add = 0;
    #pragma unroll
    for (int i = 0; i < 4; ++i)
        if (i < wv) add += wsum[i];
    __syncthreads();
    return incl + add;
}

// ---------- cooperative preproc: one dispatch ----------

__global__ __launch_bounds__(256)
void preproc_kernel(const int* __restrict__ rows, const int* __restrict__ cols,
                    const float* __restrict__ w,
                    int* __restrict__ bcount, int* __restrict__ bcur,
                    int* __restrict__ rcount, int* __restrict__ rcur,
                    int* __restrict__ boff, int* __restrict__ roff,
                    int* __restrict__ bsA, int* __restrict__ bsB,
                    int4* __restrict__ perm, int nnz) {
    cg::grid_group grid = cg::this_grid();
    __shared__ int wsum[4];
    int tid = blockIdx.x * 256 + (int)threadIdx.x;
    int nthr = gridDim.x * 256;

    // P0: zero count/cursor arrays
    for (int i = tid; i < 2 * NBUCK + 2 * N_B_CONST; i += nthr) {
        if (i < NBUCK)                      bcount[i] = 0;
        else if (i < 2 * NBUCK)             bcur[i - NBUCK] = 0;
        else if (i < 2 * NBUCK + N_B_CONST) rcount[i - 2 * NBUCK] = 0;
        else                                rcur[i - 2 * NBUCK - N_B_CONST] = 0;
    }
    grid.sync();

    // P1: dual histogram
    for (int k = tid; k < nnz; k += nthr) {
        int cf = flip_col(cols[k]);
        atomicAdd(&bcount[cf >> 4], 1);
        atomicAdd(&rcount[rows[k]], 1);
    }
    grid.sync();

    // P2a: block-local exclusive scans (A: blocks 0..NCHA-1; B: blocks 256..)
    if (blockIdx.x < NCHA) {
        int gidx = blockIdx.x * 256 + (int)threadIdx.x;
        int v = (gidx < NBUCK) ? bcount[gidx] : 0;
        int incl = block_scan_256(v, wsum);
        if (gidx < NBUCK) boff[gidx] = incl - v;
        if (threadIdx.x == 255) bsA[blockIdx.x] = incl;
    } else if (blockIdx.x >= 256 && blockIdx.x < 256 + NCHB) {
        int i = blockIdx.x - 256;
        int gidx = i * 256 + (int)threadIdx.x;
        int v = (gidx < N_B_CONST) ? rcount[gidx] : 0;
        int incl = block_scan_256(v, wsum);
        if (gidx < N_B_CONST) roff[gidx] = incl - v;
        if (threadIdx.x == 255) bsB[i] = incl;
    }
    grid.sync();

    // P2b: scan block sums; write totals
    if (blockIdx.x == 0) {
        int v = ((int)threadIdx.x < NCHA) ? bsA[threadIdx.x] : 0;
        int incl = block_scan_256(v, wsum);
        if ((int)threadIdx.x < NCHA) bsA[threadIdx.x] = incl - v;
        if (threadIdx.x == 255) boff[NBUCK] = incl;
    } else if (blockIdx.x == 1) {
        int v = ((int)threadIdx.x < NCHB) ? bsB[threadIdx.x] : 0;
        int incl = block_scan_256(v, wsum);
        if ((int)threadIdx.x < NCHB) bsB[threadIdx.x] = incl - v;
        if (threadIdx.x == 255) roff[N_B_CONST] = incl;
    }
    grid.sync();

    // P2c: add block offsets
    if (blockIdx.x < NCHA) {
        int gidx = blockIdx.x * 256 + (int)threadIdx.x;
        if (gidx < NBUCK) boff[gidx] += bsA[blockIdx.x];
    } else if (blockIdx.x >= 256 && blockIdx.x < 256 + NCHB) {
        int i = blockIdx.x - 256;
        int gidx = i * 256 + (int)threadIdx.x;
        if (gidx < N_B_CONST) roff[gidx] += bsB[i];
    }
    grid.sync();

    // P3: permute -> perm[j_cf] = (cf, w_bits, j_row)
    for (int k = tid; k < nnz; k += nthr) {
        int cf = flip_col(cols[k]);
        int bu = cf >> 4;
        int j_cf = boff[bu] + atomicAdd(&bcur[bu], 1);
        int b = rows[k];
        int j_row = roff[b] + atomicAdd(&rcur[b], 1);
        perm[j_cf] = make_int4(cf, __float_as_int(w[k]), j_row, 0);
    }
}

// ---------- hot phases (r9 verbatim) ----------

__global__ __launch_bounds__(256, 2)
void gather_kernel(const float* __restrict__ x, const int4* __restrict__ perm,
                   unsigned int* __restrict__ g, int nnz) {
    int j = blockIdx.x * 256 + (int)threadIdx.x;
    bool act = j < nnz;
    int4 p = perm[act ? j : (nnz - 1)];
    const float* xp = x + p.x;
    float wj = __int_as_float(p.y);

    unsigned int v[NPAIR];
    #pragma unroll
    for (int pp = 0; pp < NPAIR; ++pp) {
        float f0 = xp[(size_t)(2 * pp) * N_A_CONST];
        float f1 = xp[(size_t)(2 * pp + 1) * N_A_CONST];
        unsigned int lo = __half_as_ushort(__float2half(wj * f0));
        unsigned int hi = __half_as_ushort(__float2half(wj * f1));
        v[pp] = lo | (hi << 16);
    }

    if (act) {
        uint4* gp = (uint4*)(g + (size_t)p.z * GDW);
        #pragma unroll
        for (int i = 0; i < 17; ++i)
            gp[i] = make_uint4(v[4 * i], v[4 * i + 1], v[4 * i + 2], v[4 * i + 3]);
        gp[17] = make_uint4(v[68], v[69], 0u, 0u);
        #pragma unroll
        for (int i = 18; i < 24; ++i) gp[i] = make_uint4(0u, 0u, 0u, 0u);  // full lines
    }
}

__device__ __forceinline__ float h2f_lo(unsigned int d) {
    return __half2float(__ushort_as_half((unsigned short)(d & 0xffffu)));
}
__device__ __forceinline__ float h2f_hi(unsigned int d) {
    return __half2float(__ushort_as_half((unsigned short)(d >> 16)));
}

// Block = 64 rows; g rows for b contiguous -> fully sequential reads.
__global__ __launch_bounds__(256)
void reduce_kernel(const unsigned int* __restrict__ g, const int* __restrict__ roff,
                   float* __restrict__ out) {
    __shared__ float lds[64][141];
    int b0 = blockIdx.x * 64;
    int lane = threadIdx.x & 63;
    int wv = threadIdx.x >> 6;

    for (int i = 0; i < 16; ++i) {
        int bl = wv * 16 + i;
        int b = b0 + bl;
        if (b < N_B_CONST) {
            int p0 = roff[b], p1 = roff[b + 1];
            float a0 = 0.f, a1 = 0.f, a2 = 0.f, a3 = 0.f;
            for (int pos = p0; pos < p1; ++pos) {
                const unsigned int* gr = g + (size_t)pos * GDW;
                unsigned int d = gr[lane];
                a0 += h2f_lo(d); a1 += h2f_hi(d);
                if (lane < 6) {
                    unsigned int e = gr[64 + lane];
                    a2 += h2f_lo(e); a3 += h2f_hi(e);
                }
            }
            lds[bl][2 * lane]     = a0;
            lds[bl][2 * lane + 1] = a1;
            if (lane < 6) {
                lds[bl][128 + 2 * lane] = a2;
                lds[bl][129 + 2 * lane] = a3;
            }
        }
    }
    __syncthreads();

    int nb = N_B_CONST - b0; if (nb > 64) nb = 64;
    for (int idx = threadIdx.x; idx < NFIELD * 64; idx += 256) {
        int f = idx >> 6;
        int rr = idx & 63;
        if (rr < nb)
            out[(size_t)f * N_B_CONST + b0 + rr] = lds[rr][f];
    }
}

// ---------- fallback ----------

__global__ void zero_out_kernel(float* __restrict__ out, int n) {
    int i = blockIdx.x * blockDim.x + threadIdx.x;
    int stride = gridDim.x * blockDim.x;
    for (; i < n; i += stride) out[i] = 0.0f;
}

__global__ void scatter_fallback_kernel(const float* __restrict__ x, const int* __restrict__ rows,
                                        const int* __restrict__ cols, const float* __restrict__ w,
                                        float* __restrict__ out, int nnz) {
    int k = blockIdx.x * blockDim.x + threadIdx.x;
    if (k >= nnz) return;
    int n = blockIdx.y;
    int cf = flip_col(cols[k]);
    float v = w[k] * x[(size_t)n * N_A_CONST + cf];
    atomicAdd(out + (size_t)n * N_B_CONST + rows[k], v);
}

extern "C" void kernel_launch(void* const* d_in, const int* in_sizes, int n_in,
                              void* d_out, int out_size, void* d_ws, size_t ws_size,
                              hipStream_t stream) {
    const float* x    = (const float*)d_in[0];
    const int*   rows = (const int*)d_in[1];
    const int*   cols = (const int*)d_in[2];
    const float* w    = (const float*)d_in[3];
    float* out = (float*)d_out;

    int nnz    = in_sizes[1];
    int nfield = in_sizes[0] / N_A_CONST;   // 140

    // ws layout (int units)
    size_t o = 0;
    size_t bcount_o = o; o += NBUCK;
    size_t bcur_o   = o; o += NBUCK;
    size_t rcount_o = o; o += N_B_CONST;
    size_t rcur_o   = o; o += N_B_CONST;
    size_t boff_o   = o; o += NBUCK + 1;
    size_t roff_o   = o; o += N_B_CONST + 1;
    size_t bsA_o    = o; o += 256;
    size_t bsB_o    = o; o += 256;
    o = (o + 31) & ~(size_t)31;                 // 128B-align perm
    size_t perm_o   = o; o += 4 * (size_t)nnz;  // int4
    o = (o + 31) & ~(size_t)31;                 // 128B-align g
    size_t g_o      = o;
    size_t need_bytes = (g_o + (size_t)nnz * GDW) * sizeof(int);

    if (ws_size < need_bytes || nfield != NFIELD) {
        zero_out_kernel<<<2048, 256, 0, stream>>>(out, out_size);
        dim3 grid((nnz + 255) / 256, nfield);
        scatter_fallback_kernel<<<grid, 256, 0, stream>>>(x, rows, cols, w, out, nnz);
        return;
    }

    int*  wsI    = (int*)d_ws;
    int*  bcount = wsI + bcount_o;
    int*  bcur   = wsI + bcur_o;
    int*  rcount = wsI + rcount_o;
    int*  rcur   = wsI + rcur_o;
    int*  boff   = wsI + boff_o;
    int*  roff   = wsI + roff_o;
    int*  bsA    = wsI + bsA_o;
    int*  bsB    = wsI + bsB_o;
    int4* perm   = (int4*)(wsI + perm_o);
    unsigned int* g = (unsigned int*)(wsI + g_o);

    void* args[] = {
        (void*)&rows, (void*)&cols, (void*)&w,
        (void*)&bcount, (void*)&bcur, (void*)&rcount, (void*)&rcur,
        (void*)&boff, (void*)&roff, (void*)&bsA, (void*)&bsB,
        (void*)&perm, (void*)&nnz
    };
    hipLaunchCooperativeKernel((const void*)preproc_kernel,
                               dim3(PRE_BLOCKS), dim3(256), args, 0, stream);

    int nblk = (nnz + 255) / 256;   // 1019
    gather_kernel<<<nblk, 256, 0, stream>>>(x, perm, g, nnz);

    int rblk = (N_B_CONST + 63) / 64;   // 1019
    reduce_kernel<<<rblk, 256, 0, stream>>>(g, roff, out);
}

// Round 14
// 295.833 us; speedup vs baseline: 1.8330x; 1.8330x over previous
//
#include <hip/hip_runtime.h>
#include <hip/hip_fp16.h>

// Regrid: r9's proven hot path + fast preproc (LDS-coalesced scan, coarse buckets).
// y[n, b] = sum_{k: rows[k]==b} w[k] * x[n, flip(cols[k])]
// x: (140, 721*1440) f32, rows/cols: (260640,) i32, w: f32, out: (140, 181*360) f32.
//
// 6 dispatches: zero counts -> dual hist (256B bucket + row) -> LDS-tiled
// coalesced scan (2 blocks) -> permute perm[j_cf]=(cf,w,j_row) -> gather ->
// reduce. Gather (r9): thread = one cf-sorted nnz; 140 scalar x loads (wave's
// sorted cfs span ~1KB -> TA merges to ~16 lines/instr, L1 absorbs 4x line
// reuse, blocks sweep planes in lockstep -> FETCH ~584MB proven r8), packs 70
// fp16 pairs, writes one 288B g row (18 uint4) at the row-sorted slot.
// Reduce (r9): g rows for b contiguous -> fully sequential reads, f32
// accumulate, LDS transpose, coalesced out stores. No global atomics in hot
// phases; d_out fully overwritten -> no zeroing.

#define NXS 1440
#define NYS 721
#define N_A_CONST (721 * 1440)
#define N_B_CONST (181 * 360)
#define NBUCKC ((N_A_CONST + 63) / 64)  // 16,223 256B-granule buckets (cf>>6)
#define NFIELD 140
#define NPAIR (NFIELD / 2)              // 70 packed fp16 pairs
#define GDW 72                          // g row stride in dwords (288B = 18 uint4)
#define TILE 16384                      // scan tile (1024 thr x 16)

__device__ __forceinline__ int flip_col(int c) {
    int iy = c / NXS;
    int ix = c - iy * NXS;
    return (NYS - 1 - iy) * NXS + ix;
}

// ---------- preprocessing ----------

__global__ void zero_ws_kernel(int* __restrict__ p, int n) {
    int i = blockIdx.x * blockDim.x + threadIdx.x;
    int stride = gridDim.x * blockDim.x;
    for (; i < n; i += stride) p[i] = 0;
}

__global__ void hist2_kernel(const int* __restrict__ rows, const int* __restrict__ cols,
                             int* __restrict__ bcount, int* __restrict__ rcount, int nnz) {
    int k = blockIdx.x * blockDim.x + threadIdx.x;
    if (k >= nnz) return;
    int cf = flip_col(cols[k]);
    atomicAdd(&bcount[cf >> 6], 1);
    atomicAdd(&rcount[rows[k]], 1);
}

// LDS-tiled coalesced exclusive scan. Block 0: bcount->boff (NBUCKC, 1 tile);
// block 1: rcount->roff (N_B, 4 tiles). out[n] = total.
__global__ __launch_bounds__(1024)
void scan_lds_kernel(const int* __restrict__ bcount, int* __restrict__ boff,
                     const int* __restrict__ rcount, int* __restrict__ roff) {
    __shared__ int tile[TILE];
    __shared__ int wsum[16];
    __shared__ int carry_s;
    const int* in; int* out; int n;
    if (blockIdx.x == 0) { in = bcount; out = boff; n = NBUCKC; }
    else                 { in = rcount; out = roff; n = N_B_CONST; }
    int t = threadIdx.x;
    int lane = t & 63, wv = t >> 6;
    if (t == 0) carry_s = 0;
    __syncthreads();

    for (int base = 0; base < n; base += TILE) {
        #pragma unroll
        for (int i = 0; i < 16; ++i) {
            int idx = base + i * 1024 + t;
            tile[i * 1024 + t] = (idx < n) ? in[idx] : 0;   // coalesced
        }
        __syncthreads();
        int s = 0;
        #pragma unroll
        for (int i = 0; i < 16; ++i) s += tile[t * 16 + i];

        int incl = s;
        #pragma unroll
        for (int off = 1; off < 64; off <<= 1) {
            int u = __shfl_up(incl, off, 64);
            if (lane >= off) incl += u;
        }
        if (lane == 63) wsum[wv] = incl;
        __syncthreads();
        if (t < 16) {
            int v = wsum[t];
            #pragma unroll
            for (int off = 1; off < 16; off <<= 1) {
                int u = __shfl_up(v, off, 16);
                if (t >= off) v += u;
            }
            wsum[t] = v;
        }
        __syncthreads();
        int waveoff = (wv == 0) ? 0 : wsum[wv - 1];
        int carry = carry_s;
        int run = carry + waveoff + incl - s;   // global exclusive prefix
        #pragma unroll
        for (int i = 0; i < 16; ++i) {
            int old = tile[t * 16 + i];
            tile[t * 16 + i] = run;
            run += old;
        }
        __syncthreads();
        if (t == 1023) carry_s = run;           // carry + tile total
        #pragma unroll
        for (int i = 0; i < 16; ++i) {
            int idx = base + i * 1024 + t;
            if (idx < n) out[idx] = tile[i * 1024 + t];   // coalesced
        }
        __syncthreads();
    }
    if (t == 0) out[n] = carry_s;
}

// perm[j_cf] = (cf, w_bits, j_row, 0)
__global__ void perm2_kernel(const int* __restrict__ rows, const int* __restrict__ cols,
                             const float* __restrict__ w,
                             const int* __restrict__ boff, int* __restrict__ bcur,
                             const int* __restrict__ roff, int* __restrict__ rcur,
                             int4* __restrict__ perm, int nnz) {
    int k = blockIdx.x * blockDim.x + threadIdx.x;
    if (k >= nnz) return;
    int cf = flip_col(cols[k]);
    int bu = cf >> 6;
    int j_cf = boff[bu] + atomicAdd(&bcur[bu], 1);
    int b = rows[k];
    int j_row = roff[b] + atomicAdd(&rcur[b], 1);
    perm[j_cf] = make_int4(cf, __float_as_int(w[k]), j_row, 0);
}

// ---------- hot phases (r9 verbatim, GDW=72) ----------

__global__ __launch_bounds__(256, 2)
void gather_kernel(const float* __restrict__ x, const int4* __restrict__ perm,
                   unsigned int* __restrict__ g, int nnz) {
    int j = blockIdx.x * 256 + (int)threadIdx.x;
    bool act = j < nnz;
    int4 p = perm[act ? j : (nnz - 1)];
    const float* xp = x + p.x;
    float wj = __int_as_float(p.y);

    unsigned int v[NPAIR];
    #pragma unroll
    for (int pp = 0; pp < NPAIR; ++pp) {
        float f0 = xp[(size_t)(2 * pp) * N_A_CONST];
        float f1 = xp[(size_t)(2 * pp + 1) * N_A_CONST];
        unsigned int lo = __half_as_ushort(__float2half(wj * f0));
        unsigned int hi = __half_as_ushort(__float2half(wj * f1));
        v[pp] = lo | (hi << 16);
    }

    if (act) {
        uint4* gp = (uint4*)(g + (size_t)p.z * GDW);
        #pragma unroll
        for (int i = 0; i < 17; ++i)
            gp[i] = make_uint4(v[4 * i], v[4 * i + 1], v[4 * i + 2], v[4 * i + 3]);
        gp[17] = make_uint4(v[68], v[69], 0u, 0u);
    }
}

__device__ __forceinline__ float h2f_lo(unsigned int d) {
    return __half2float(__ushort_as_half((unsigned short)(d & 0xffffu)));
}
__device__ __forceinline__ float h2f_hi(unsigned int d) {
    return __half2float(__ushort_as_half((unsigned short)(d >> 16)));
}

// Block = 64 rows; g rows for b contiguous -> fully sequential reads.
__global__ __launch_bounds__(256)
void reduce_kernel(const unsigned int* __restrict__ g, const int* __restrict__ roff,
                   float* __restrict__ out) {
    __shared__ float lds[64][141];
    int b0 = blockIdx.x * 64;
    int lane = threadIdx.x & 63;
    int wv = threadIdx.x >> 6;

    for (int i = 0; i < 16; ++i) {
        int bl = wv * 16 + i;
        int b = b0 + bl;
        if (b < N_B_CONST) {
            int p0 = roff[b], p1 = roff[b + 1];
            float a0 = 0.f, a1 = 0.f, a2 = 0.f, a3 = 0.f;
            for (int pos = p0; pos < p1; ++pos) {
                const unsigned int* gr = g + (size_t)pos * GDW;
                unsigned int d = gr[lane];
                a0 += h2f_lo(d); a1 += h2f_hi(d);
                if (lane < 6) {
                    unsigned int e = gr[64 + lane];
                    a2 += h2f_lo(e); a3 += h2f_hi(e);
                }
            }
            lds[bl][2 * lane]     = a0;
            lds[bl][2 * lane + 1] = a1;
            if (lane < 6) {
                lds[bl][128 + 2 * lane] = a2;
                lds[bl][129 + 2 * lane] = a3;
            }
        }
    }
    __syncthreads();

    int nb = N_B_CONST - b0; if (nb > 64) nb = 64;
    for (int idx = threadIdx.x; idx < NFIELD * 64; idx += 256) {
        int f = idx >> 6;
        int rr = idx & 63;
        if (rr < nb)
            out[(size_t)f * N_B_CONST + b0 + rr] = lds[rr][f];
    }
}

// ---------- fallback ----------

__global__ void zero_out_kernel(float* __restrict__ out, int n) {
    int i = blockIdx.x * blockDim.x + threadIdx.x;
    int stride = gridDim.x * blockDim.x;
    for (; i < n; i += stride) out[i] = 0.0f;
}

__global__ void scatter_fallback_kernel(const float* __restrict__ x, const int* __restrict__ rows,
                                        const int* __restrict__ cols, const float* __restrict__ w,
                                        float* __restrict__ out, int nnz) {
    int k = blockIdx.x * blockDim.x + threadIdx.x;
    if (k >= nnz) return;
    int n = blockIdx.y;
    int cf = flip_col(cols[k]);
    float v = w[k] * x[(size_t)n * N_A_CONST + cf];
    atomicAdd(out + (size_t)n * N_B_CONST + rows[k], v);
}

extern "C" void kernel_launch(void* const* d_in, const int* in_sizes, int n_in,
                              void* d_out, int out_size, void* d_ws, size_t ws_size,
                              hipStream_t stream) {
    const float* x    = (const float*)d_in[0];
    const int*   rows = (const int*)d_in[1];
    const int*   cols = (const int*)d_in[2];
    const float* w    = (const float*)d_in[3];
    float* out = (float*)d_out;

    int nnz    = in_sizes[1];
    int nfield = in_sizes[0] / N_A_CONST;   // 140

    // ws layout (int units). Count/cursor arrays first: zeroed by one kernel.
    size_t o = 0;
    size_t bcount_o = o; o += NBUCKC;
    size_t bcur_o   = o; o += NBUCKC;
    size_t rcount_o = o; o += N_B_CONST;
    size_t rcur_o   = o; o += N_B_CONST;
    size_t zero_span = o;
    size_t boff_o   = o; o += NBUCKC + 1;
    size_t roff_o   = o; o += N_B_CONST + 1;
    o = (o + 31) & ~(size_t)31;                 // 128B-align perm
    size_t perm_o   = o; o += 4 * (size_t)nnz;  // int4
    o = (o + 31) & ~(size_t)31;                 // 128B-align g
    size_t g_o      = o;
    size_t need_bytes = (g_o + (size_t)nnz * GDW) * sizeof(int);

    if (ws_size < need_bytes || nfield != NFIELD) {
        zero_out_kernel<<<2048, 256, 0, stream>>>(out, out_size);
        dim3 grid((nnz + 255) / 256, nfield);
        scatter_fallback_kernel<<<grid, 256, 0, stream>>>(x, rows, cols, w, out, nnz);
        return;
    }

    int*  wsI    = (int*)d_ws;
    int*  bcount = wsI + bcount_o;
    int*  bcur   = wsI + bcur_o;
    int*  rcount = wsI + rcount_o;
    int*  rcur   = wsI + rcur_o;
    int*  boff   = wsI + boff_o;
    int*  roff   = wsI + roff_o;
    int4* perm   = (int4*)(wsI + perm_o);
    unsigned int* g = (unsigned int*)(wsI + g_o);

    zero_ws_kernel<<<512, 256, 0, stream>>>(wsI, (int)zero_span);

    int nblk = (nnz + 255) / 256;   // 1019
    hist2_kernel<<<nblk, 256, 0, stream>>>(rows, cols, bcount, rcount, nnz);
    scan_lds_kernel<<<2, 1024, 0, stream>>>(bcount, boff, rcount, roff);
    perm2_kernel<<<nblk, 256, 0, stream>>>(rows, cols, w, boff, bcur, roff, rcur, perm, nnz);

    gather_kernel<<<nblk, 256, 0, stream>>>(x, perm, g, nnz);

    int rblk = (N_B_CONST + 63) / 64;   // 1019
    reduce_kernel<<<rblk, 256, 0, stream>>>(g, roff, out);
}